// Round 8
// baseline (396.637 us; speedup 1.0000x reference)
//
#include <hip/hip_runtime.h>
#include <hip/hip_cooperative_groups.h>
#include <cstddef>

namespace cg = cooperative_groups;

typedef unsigned short u16;
typedef u16 u16x4 __attribute__((ext_vector_type(4)));
typedef u16 u16x8 __attribute__((ext_vector_type(8)));
typedef __bf16 bf16x8 __attribute__((ext_vector_type(8)));
typedef float f32x4 __attribute__((ext_vector_type(4)));

static constexpr int V  = 2048;
static constexpr int DD = 64;   // D_IN == D_OUT

__device__ __forceinline__ u16 f2b(float f) {
  union { float f; unsigned int i; } x; x.f = f;
  return (u16)((x.i + 0x7fffu + ((x.i >> 16) & 1u)) >> 16);  // RNE
}

__device__ __forceinline__ void gll16(const void* g, void* l) {
  __builtin_amdgcn_global_load_lds(
      (const __attribute__((address_space(1))) void*)g,
      (__attribute__((address_space(3))) void*)l, 16, 0, 0);
}

// ---- R8: single cooperative mega-kernel ----
// Evidence R5-R7: kernel work below the 41.7us fill threshold is only
// ~15-20us of BW-floor work, but total-fill-gemm ~ 56us -> ~35-40us is
// dispatch-boundary overhead (R5->R6: one launch removed = -10us).
// Fuse all stages; grid.sync() between phases (harness-supported).
// Geometry: 512 blocks x 256 thr, 64KB LDS -> exactly 2 blocks/CU
// co-resident (LDS-limited), launch_bounds(256,2).
// Phase bodies are the measured R6/R7 kernels, re-indexed:
//   1a part: partial[64][2048], 32-row sums (512 blocks)
//   1b proj: 2 tiles/block, swapped-operand MFMA, u16x4 Yt stores (R7)
//   sync; 2 tn: 2 tiles/block, inline rinv (64 adds, L2-hot partial)
//   sync; 3 gemm: R4-frozen body (42.4us / ~810TF / 0 bank conflicts)
static constexpr int ABUF  = 128 * 64;          // u16 units, 16 KB
static constexpr int BUFSZ = 2 * ABUF;          // 32 KB (A + B)

__global__ __launch_bounds__(256, 2) void k_mega(
    const float* __restrict__ adj, const float* __restrict__ x,
    const float* __restrict__ w, const float* __restrict__ bias,
    float* __restrict__ partial, u16* __restrict__ At,
    u16* __restrict__ Yt, float* __restrict__ out) {
  __shared__ u16 lds[2 * BUFSZ];                // 64 KB, aliased per phase
  const int t = threadIdx.x;
  const int bid = blockIdx.x;
  const int lane = t & 63, wave = t >> 6;
  const int q = lane >> 4, r = lane & 15;

  // ================= Phase 1a: part =================
  // partial[rg][col] = sum of 32 adj rows; rg=bid>>3 (64 groups), cg=bid&7.
  {
    int rg = bid >> 3, cg = bid & 7;
    int col = cg * 256 + t;
    const float* p = adj + (size_t)(rg * 32) * V + col;
    float s = 0.f;
    for (int rr = 0; rr < 32; ++rr) s += p[(size_t)rr * V];
    partial[(size_t)rg * V + col] = s;
  }

  // ================= Phase 1b: proj =================
  // Yt[(ab*64+e)][v] = sum_d W[d][e]*x[ab,v,d]; 2 tiles per block.
  {
    u16* WT = lds;   // W^T bf16, stride 72 (9 KB)
    {
      const float4* pw = (const float4*)(w + t * 16);
      float4 c0 = pw[0], c1 = pw[1], c2 = pw[2], c3 = pw[3];
      float vals[16] = {c0.x, c0.y, c0.z, c0.w, c1.x, c1.y, c1.z, c1.w,
                        c2.x, c2.y, c2.z, c2.w, c3.x, c3.y, c3.z, c3.w};
      #pragma unroll
      for (int k = 0; k < 16; ++k) {
        int idx = t * 16 + k;             // idx = d*64 + e
        WT[(idx & 63) * 72 + (idx >> 6)] = f2b(vals[k]);
      }
    }
    __syncthreads();

    // W fragment (B-operand): lane r -> e, q -> d-chunk. Loaded once.
    bf16x8 a[4][2];
    #pragma unroll
    for (int i = 0; i < 4; ++i)
      #pragma unroll
      for (int kk = 0; kk < 2; ++kk)
        a[i][kk] = __builtin_bit_cast(bf16x8,
            *(const u16x8*)(WT + (i * 16 + r) * 72 + kk * 32 + q * 8));

    const f32x4 vzero = {0.f, 0.f, 0.f, 0.f};
    #pragma unroll
    for (int sub = 0; sub < 2; ++sub) {
      int pb = bid * 2 + sub;
      int ab = pb >> 4;
      int v0 = (pb & 15) * 128;
      int vbase = v0 + wave * 32;

      f32x4 acc[4][2];
      #pragma unroll
      for (int i = 0; i < 4; ++i) { acc[i][0] = vzero; acc[i][1] = vzero; }

      #pragma unroll
      for (int nt = 0; nt < 2; ++nt) {
        int v = vbase + nt * 16 + r;
        const float* xp = x + ((size_t)ab * V + v) * DD;
        #pragma unroll
        for (int kk = 0; kk < 2; ++kk) {
          const float4* p = (const float4*)(xp + kk * 32 + q * 8);
          float4 b0 = p[0], b1 = p[1];
          u16x8 bu;
          bu[0] = f2b(b0.x); bu[1] = f2b(b0.y); bu[2] = f2b(b0.z); bu[3] = f2b(b0.w);
          bu[4] = f2b(b1.x); bu[5] = f2b(b1.y); bu[6] = f2b(b1.z); bu[7] = f2b(b1.w);
          bf16x8 bf = __builtin_bit_cast(bf16x8, bu);  // A-frag: m=v
          #pragma unroll
          for (int i = 0; i < 4; ++i)
            acc[i][nt] = __builtin_amdgcn_mfma_f32_16x16x32_bf16(bf, a[i][kk], acc[i][nt], 0, 0, 0);
        }
      }

      // D: col(r)=e-offset, row(q*4+reg)=v-offset -> u16x4 along v.
      #pragma unroll
      for (int i = 0; i < 4; ++i) {
        int e = ab * 64 + i * 16 + r;
        #pragma unroll
        for (int nt = 0; nt < 2; ++nt) {
          int v = vbase + nt * 16 + q * 4;
          u16x4 o;
          #pragma unroll
          for (int reg = 0; reg < 4; ++reg) o[reg] = f2b(acc[i][nt][reg]);
          *(u16x4*)(Yt + (size_t)e * V + v) = o;
        }
      }
    }
  }

  __threadfence();
  cg::this_grid().sync();

  // ================= Phase 2: tn =================
  // At[j][v] = adj[v][j]*rinv[v]*rinv[j]; 2 tiles per block.
  {
    float (*T)[65] = (float(*)[65])lds;              // 16640 B
    float* rvv = (float*)((char*)lds + 17408);       // 256 B
    float* rvj = (float*)((char*)lds + 17664);       // 256 B

    #pragma unroll
    for (int sub = 0; sub < 2; ++sub) {
      int tb = bid * 2 + sub;
      int v0 = (tb & 31) * 64;
      int j0 = (tb >> 5) * 64;

      if (sub) __syncthreads();   // protect T/rvv/rvj reuse
      if (t < 128) {
        int col = (t < 64) ? (v0 + t) : (j0 + (t - 64));
        float s = 0.f;
        #pragma unroll
        for (int i = 0; i < 64; ++i) s += partial[(size_t)i * V + col];
        float rv = rsqrtf(s);
        if (t < 64) rvv[t] = rv; else rvj[t - 64] = rv;
      }
      __syncthreads();
      #pragma unroll
      for (int it = 0; it < 2; ++it) {
        int f = t + it * 256;
        int row = f >> 3;          // v offset
        int cc = (f & 7) * 8;      // j chunk
        float rv = rvv[row];
        const float4* p = (const float4*)(adj + (size_t)(v0 + row) * V + j0 + cc);
        float4 a0 = p[0], a1 = p[1];
        T[row][cc + 0] = a0.x * rv; T[row][cc + 1] = a0.y * rv;
        T[row][cc + 2] = a0.z * rv; T[row][cc + 3] = a0.w * rv;
        T[row][cc + 4] = a1.x * rv; T[row][cc + 5] = a1.y * rv;
        T[row][cc + 6] = a1.z * rv; T[row][cc + 7] = a1.w * rv;
      }
      __syncthreads();
      #pragma unroll
      for (int it = 0; it < 2; ++it) {
        int f = t + it * 256;
        int jr = f >> 3;           // j offset
        int vc = (f & 7) * 8;      // v chunk
        float rj = rvj[jr];
        u16x8 o;
        #pragma unroll
        for (int k = 0; k < 8; ++k) o[k] = f2b(T[vc + k][jr] * rj);
        *(u16x8*)(At + (size_t)(j0 + jr) * V + v0 + vc) = o;
      }
    }
  }

  __threadfence();
  cg::this_grid().sync();

  // ================= Phase 3: gemm (R4-frozen) =================
  {
    const int swz = (bid & 7) * 64 + (bid >> 3);  // XCD-chunked, bijective
    const int m0 = (swz & 15) * 128;
    const int n0 = (swz >> 4) * 128;
    const int wm = (wave & 1) * 64;
    const int wn = (wave >> 1) * 64;

    auto stage = [&](int base, int k0) {
      #pragma unroll
      for (int l = 0; l < 4; ++l) {
        int g = l * 256 + t;
        int row = g >> 3;
        int ch = (g & 7) ^ (row & 7);
        gll16(At + (size_t)(m0 + row) * V + k0 + ch * 8, (void*)(lds + base + g * 8));
        gll16(Yt + (size_t)(n0 + row) * V + k0 + ch * 8, (void*)(lds + base + ABUF + g * 8));
      }
    };

    const f32x4 vzero = {0.f, 0.f, 0.f, 0.f};
    f32x4 acc[4][4];
    #pragma unroll
    for (int i = 0; i < 4; ++i)
      #pragma unroll
      for (int j = 0; j < 4; ++j) acc[i][j] = vzero;

    stage(0, 0);
    asm volatile("s_waitcnt vmcnt(0)" ::: "memory");
    __builtin_amdgcn_s_barrier();

    int cb = 0;
    for (int tt = 0; tt < 32; ++tt) {
      const int nb = cb ^ BUFSZ;
      if (tt < 31) stage(nb, (tt + 1) * 64);
      __builtin_amdgcn_sched_barrier(0);   // keep stage issues at phase top

      #pragma unroll
      for (int kk = 0; kk < 2; ++kk) {
        bf16x8 a[4], b[4];
        #pragma unroll
        for (int i = 0; i < 4; ++i) {
          int row = wm + i * 16 + r;
          int c = (kk * 4 + q) ^ (row & 7);
          a[i] = __builtin_bit_cast(bf16x8,
              *(const u16x8*)(lds + cb + row * 64 + c * 8));
        }
        #pragma unroll
        for (int j = 0; j < 4; ++j) {
          int row = wn + j * 16 + r;
          int c = (kk * 4 + q) ^ (row & 7);
          b[j] = __builtin_bit_cast(bf16x8,
              *(const u16x8*)(lds + cb + ABUF + row * 64 + c * 8));
        }
        __builtin_amdgcn_s_setprio(1);
        #pragma unroll
        for (int i = 0; i < 4; ++i)
          #pragma unroll
          for (int j = 0; j < 4; ++j)
            acc[i][j] = __builtin_amdgcn_mfma_f32_16x16x32_bf16(
                a[i], b[j], acc[i][j], 0, 0, 0);
        __builtin_amdgcn_s_setprio(0);
      }

      asm volatile("s_waitcnt vmcnt(0)" ::: "memory");
      __builtin_amdgcn_s_barrier();
      cb = nb;
    }

    #pragma unroll
    for (int j = 0; j < 4; ++j) {
      int n = n0 + wn + j * 16 + r;
      int e = n & 63;
      int ab = n >> 6;
      float bv = bias[e];
      float* ob = out + (size_t)ab * (V * DD);
      #pragma unroll
      for (int i = 0; i < 4; ++i) {
        #pragma unroll
        for (int reg = 0; reg < 4; ++reg) {
          int jj = m0 + wm + i * 16 + q * 4 + reg;
          ob[(size_t)jj * DD + e] = fmaxf(acc[i][j][reg] + bv, 0.f);
        }
      }
    }
  }
}

extern "C" void kernel_launch(void* const* d_in, const int* in_sizes, int n_in,
                              void* d_out, int out_size, void* d_ws, size_t ws_size,
                              hipStream_t stream) {
  const float* adj  = (const float*)d_in[0];
  const float* x    = (const float*)d_in[1];
  const float* w    = (const float*)d_in[2];
  const float* bias = (const float*)d_in[3];
  float* out = (float*)d_out;

  // Workspace (24.5 MB):
  //   At      @ 0     : 2048*2048 bf16 = 8 MB    (phase 2 -> 3)
  //   Yt      @ 8 MB  : 4096*2048 bf16 = 16 MB   (phase 1b -> 3)
  //   partial @ 24 MB : 64*2048 f32 = 512 KB     (phase 1a -> 2)
  char* ws = (char*)d_ws;
  u16*   At      = (u16*)ws;
  u16*   Yt      = (u16*)(ws + ((size_t)8 << 20));
  float* partial = (float*)(ws + ((size_t)24 << 20));

  void* args[] = {(void*)&adj, (void*)&x, (void*)&w, (void*)&bias,
                  (void*)&partial, (void*)&At, (void*)&Yt, (void*)&out};
  hipLaunchCooperativeKernel((void*)k_mega, dim3(512), dim3(256), args, 0, stream);
}

// Round 10
// 149.030 us; speedup vs baseline: 2.6615x; 2.6615x over previous
//
#include <hip/hip_runtime.h>
#include <cstddef>

typedef unsigned short u16;
typedef u16 u16x8 __attribute__((ext_vector_type(8)));
typedef __bf16 bf16x8 __attribute__((ext_vector_type(8)));
typedef float f32x4 __attribute__((ext_vector_type(4)));

static constexpr int V  = 2048;
static constexpr int DD = 64;   // D_IN == D_OUT

__device__ __forceinline__ u16 f2b(float f) {
  union { float f; unsigned int i; } x; x.f = f;
  return (u16)((x.i + 0x7fffu + ((x.i >> 16) & 1u)) >> 16);  // RNE
}

__device__ __forceinline__ void gll16(const void* g, void* l) {
  __builtin_amdgcn_global_load_lds(
      (const __attribute__((address_space(1))) void*)g,
      (__attribute__((address_space(3))) void*)l, 16, 0, 0);
}

// ---- K1 fused: blocks 0..255 = column-sum partials; 256..1279 = proj ----
// R6 form (best total 140.6us). R8 cooperative fusion REVERTED: two
// cg::grid().sync()s cost ~230us on 8-XCD MI355X (k_mega 300us vs ~65us
// of phase work) -- stream boundaries (~10us) are 10x cheaper.
__global__ __launch_bounds__(256) void k_pp(const float* __restrict__ adj,
                                            const float* __restrict__ x,
                                            const float* __restrict__ w,
                                            float* __restrict__ partial,
                                            u16* __restrict__ Yt) {
  __shared__ u16 WT[64 * 72];   // proj: W^T bf16, stride 72 (9 KB)
  int t = threadIdx.x;
  int bid = blockIdx.x;

  if (bid < 256) {
    // ---------- part: partial[rg][col] = sum of 64 adj rows ----------
    int rg = bid >> 3, cg = bid & 7;
    int col = cg * 256 + t;
    const float* p = adj + (size_t)(rg * 64) * V + col;
    float s = 0.f;
    for (int r = 0; r < 64; ++r) s += p[(size_t)r * V];
    partial[(size_t)rg * V + col] = s;
  } else {
    // ---------- proj (MFMA): Yt[(ab*64+e)][v] = sum_d W[d][e]*x[ab,v,d] ----
    int pb = bid - 256;
    int ab = pb >> 4;
    int v0 = (pb & 15) * 128;

    {
      const float4* pw = (const float4*)(w + t * 16);
      float4 c0 = pw[0], c1 = pw[1], c2 = pw[2], c3 = pw[3];
      float vals[16] = {c0.x, c0.y, c0.z, c0.w, c1.x, c1.y, c1.z, c1.w,
                        c2.x, c2.y, c2.z, c2.w, c3.x, c3.y, c3.z, c3.w};
      #pragma unroll
      for (int k = 0; k < 16; ++k) {
        int idx = t * 16 + k;             // idx = d*64 + e
        WT[(idx & 63) * 72 + (idx >> 6)] = f2b(vals[k]);
      }
    }
    __syncthreads();

    int lane = t & 63, wave = t >> 6;
    int q = lane >> 4, r = lane & 15;
    int vbase = v0 + wave * 32;

    bf16x8 a[4][2];
    #pragma unroll
    for (int i = 0; i < 4; ++i)
      #pragma unroll
      for (int kk = 0; kk < 2; ++kk)
        a[i][kk] = __builtin_bit_cast(bf16x8,
            *(const u16x8*)(WT + (i * 16 + r) * 72 + kk * 32 + q * 8));

    const f32x4 vzero = {0.f, 0.f, 0.f, 0.f};
    f32x4 acc[4][2];
    #pragma unroll
    for (int i = 0; i < 4; ++i) { acc[i][0] = vzero; acc[i][1] = vzero; }

    #pragma unroll
    for (int nt = 0; nt < 2; ++nt) {
      int v = vbase + nt * 16 + r;
      const float* xp = x + ((size_t)ab * V + v) * DD;
      #pragma unroll
      for (int kk = 0; kk < 2; ++kk) {
        const float4* p = (const float4*)(xp + kk * 32 + q * 8);
        float4 b0 = p[0], b1 = p[1];
        u16x8 bu;
        bu[0] = f2b(b0.x); bu[1] = f2b(b0.y); bu[2] = f2b(b0.z); bu[3] = f2b(b0.w);
        bu[4] = f2b(b1.x); bu[5] = f2b(b1.y); bu[6] = f2b(b1.z); bu[7] = f2b(b1.w);
        bf16x8 bf = __builtin_bit_cast(bf16x8, bu);
        #pragma unroll
        for (int i = 0; i < 4; ++i)
          acc[i][nt] = __builtin_amdgcn_mfma_f32_16x16x32_bf16(a[i][kk], bf, acc[i][nt], 0, 0, 0);
      }
    }

    #pragma unroll
    for (int i = 0; i < 4; ++i)
      #pragma unroll
      for (int nt = 0; nt < 2; ++nt) {
        int v = vbase + nt * 16 + r;
        #pragma unroll
        for (int reg = 0; reg < 4; ++reg) {
          int e = i * 16 + q * 4 + reg;
          Yt[(size_t)(ab * 64 + e) * V + v] = f2b(acc[i][nt][reg]);
        }
      }
  }
}

// ---- K2: tn tiles with inline rinv: At[j][v] = adj[v][j]*rinv[v]*rinv[j] --
// rinv from partial[32][2048] (256 KB, L2-hot): 32 adds per column.
__global__ __launch_bounds__(256) void k_tn(const float* __restrict__ adj,
                                            const float* __restrict__ partial,
                                            u16* __restrict__ At) {
  __shared__ float T[64][65];
  __shared__ float rvv[64], rvj[64];
  int t = threadIdx.x;
  int bid = blockIdx.x;
  int v0 = (bid & 31) * 64;
  int j0 = (bid >> 5) * 64;

  if (t < 128) {
    int col = (t < 64) ? (v0 + t) : (j0 + (t - 64));
    float s = 0.f;
    #pragma unroll
    for (int i = 0; i < 32; ++i) s += partial[(size_t)i * V + col];
    float rv = rsqrtf(s);
    if (t < 64) rvv[t] = rv; else rvj[t - 64] = rv;
  }
  __syncthreads();
  #pragma unroll
  for (int it = 0; it < 2; ++it) {
    int f = t + it * 256;
    int row = f >> 3;          // v offset
    int cc = (f & 7) * 8;      // j chunk
    float rv = rvv[row];
    const float4* p = (const float4*)(adj + (size_t)(v0 + row) * V + j0 + cc);
    float4 a0 = p[0], a1 = p[1];
    T[row][cc + 0] = a0.x * rv; T[row][cc + 1] = a0.y * rv;
    T[row][cc + 2] = a0.z * rv; T[row][cc + 3] = a0.w * rv;
    T[row][cc + 4] = a1.x * rv; T[row][cc + 5] = a1.y * rv;
    T[row][cc + 6] = a1.z * rv; T[row][cc + 7] = a1.w * rv;
  }
  __syncthreads();
  #pragma unroll
  for (int it = 0; it < 2; ++it) {
    int f = t + it * 256;
    int jr = f >> 3;           // j offset
    int vc = (f & 7) * 8;      // v chunk
    float rj = rvj[jr];
    u16x8 o;
    #pragma unroll
    for (int k = 0; k < 8; ++k) o[k] = f2b(T[vc + k][jr] * rj);
    *(u16x8*)(At + (size_t)(j0 + jr) * V + v0 + vc) = o;
  }
}

// ---- K3: OUT[j,n] = sum_v At[j,v]*Yt[n,v]; +bias, relu; FP32 out ----
// R9: R4 geometry (BM=BN=128, 4 waves 64x64, 512 blocks = 2/CU) +
// COUNTED vmcnt via BK=32 TRIPLE buffer (48 KB): per iter stage 4 gll16
// into tile t+2; end-of-iter vmcnt(4) waits only tile t+1 -- tile t+2's
// loads stay in flight across the barrier (T4; R4's vmcnt(0) drain was
// the ~25% realization gap: ceiling 41% LDS-bound vs 30% measured).
// Swizzle ch = cl ^ ((row>>1)&3): 16 frag rows -> 8 bank-starts -> 2-way
// max (free, m136). Same MFMA order as R4 -> bitwise-identical out.
static constexpr int ABUF  = 128 * 32;          // u16 units, 8 KB
static constexpr int BUFSZ = 2 * ABUF;          // 16 KB (A + B)

__global__ __launch_bounds__(256) void k_gemm(const u16* __restrict__ At,
                                              const u16* __restrict__ Yt,
                                              const float* __restrict__ bias,
                                              float* __restrict__ out) {
  __shared__ u16 lds[3 * BUFSZ];                // 48 KB
  const int t = threadIdx.x;
  const int bid = blockIdx.x;
  const int swz = (bid & 7) * 64 + (bid >> 3);  // XCD-chunked, bijective
  const int m0 = (swz & 15) * 128;
  const int n0 = (swz >> 4) * 128;
  const int lane = t & 63, wave = t >> 6;
  const int wm = (wave & 1) * 64;
  const int wn = (wave >> 1) * 64;
  const int q = lane >> 4, r = lane & 15;

  // stage one K-32 tile: A 128x32 (2 granules/thr) + B same (2/thr).
  // LDS slot (row, cl) holds logical chunk cl ^ ((row>>1)&3).
  auto stage = [&](int base, int k0) {
    #pragma unroll
    for (int l = 0; l < 2; ++l) {
      int g = l * 256 + t;
      int row = g >> 2;
      int ch = (g & 3) ^ ((row >> 1) & 3);
      gll16(At + (size_t)(m0 + row) * V + k0 + ch * 8, (void*)(lds + base + g * 8));
      gll16(Yt + (size_t)(n0 + row) * V + k0 + ch * 8, (void*)(lds + base + ABUF + g * 8));
    }
  };

  const f32x4 vzero = {0.f, 0.f, 0.f, 0.f};
  f32x4 acc[4][4];
  #pragma unroll
  for (int i = 0; i < 4; ++i)
    #pragma unroll
    for (int j = 0; j < 4; ++j) acc[i][j] = vzero;

  // prologue: stage tiles 0,1 (8 loads); wait tile 0 only (vmcnt(4)).
  stage(0, 0);
  stage(BUFSZ, 32);
  asm volatile("s_waitcnt vmcnt(4)" ::: "memory");
  __builtin_amdgcn_s_barrier();

  int c0 = 0, c1 = BUFSZ, c2 = 2 * BUFSZ;       // rotating buffer bases
  for (int tt = 0; tt < 64; ++tt) {
    if (tt < 62) stage(c2, (tt + 2) * 32);       // tile t+2 into free buf
    __builtin_amdgcn_sched_barrier(0);           // keep issues at phase top

    bf16x8 a[4], b[4];
    #pragma unroll
    for (int i = 0; i < 4; ++i) {
      int row = wm + i * 16 + r;
      int ch = q ^ ((row >> 1) & 3);
      a[i] = __builtin_bit_cast(bf16x8,
          *(const u16x8*)(lds + c0 + row * 32 + ch * 8));
    }
    #pragma unroll
    for (int j = 0; j < 4; ++j) {
      int row = wn + j * 16 + r;
      int ch = q ^ ((row >> 1) & 3);
      b[j] = __builtin_bit_cast(bf16x8,
          *(const u16x8*)(lds + c0 + ABUF + row * 32 + ch * 8));
    }
    __builtin_amdgcn_s_setprio(1);
    #pragma unroll
    for (int i = 0; i < 4; ++i)
      #pragma unroll
      for (int j = 0; j < 4; ++j)
        acc[i][j] = __builtin_amdgcn_mfma_f32_16x16x32_bf16(
            a[i], b[j], acc[i][j], 0, 0, 0);
    __builtin_amdgcn_s_setprio(0);

    if (tt < 62)       asm volatile("s_waitcnt vmcnt(4)" ::: "memory");
    else if (tt == 62) asm volatile("s_waitcnt vmcnt(0)" ::: "memory");
    __builtin_amdgcn_s_barrier();
    int tmp = c0; c0 = c1; c1 = c2; c2 = tmp;    // rotate
  }

  // epilogue: D mapping col=lane&15, row=q*4+reg (verified form).
  #pragma unroll
  for (int j = 0; j < 4; ++j) {
    int n = n0 + wn + j * 16 + r;
    int e = n & 63;
    int ab = n >> 6;
    float bv = bias[e];
    float* ob = out + (size_t)ab * (V * DD);
    #pragma unroll
    for (int i = 0; i < 4; ++i) {
      #pragma unroll
      for (int reg = 0; reg < 4; ++reg) {
        int jj = m0 + wm + i * 16 + q * 4 + reg;
        ob[(size_t)jj * DD + e] = fmaxf(acc[i][j][reg] + bv, 0.f);
      }
    }
  }
}

extern "C" void kernel_launch(void* const* d_in, const int* in_sizes, int n_in,
                              void* d_out, int out_size, void* d_ws, size_t ws_size,
                              hipStream_t stream) {
  const float* adj  = (const float*)d_in[0];
  const float* x    = (const float*)d_in[1];
  const float* w    = (const float*)d_in[2];
  const float* bias = (const float*)d_in[3];
  float* out = (float*)d_out;

  // Workspace (24.25 MB):
  //   At      @ 0     : 2048*2048 bf16 = 8 MB    (live k_tn..k_gemm)
  //   Yt      @ 8 MB  : 4096*2048 bf16 = 16 MB   (live k_pp..k_gemm)
  //   partial @ 24 MB : 32*2048 f32 = 256 KB     (live k_pp..k_tn)
  char* ws = (char*)d_ws;
  u16*   At      = (u16*)ws;
  u16*   Yt      = (u16*)(ws + ((size_t)8 << 20));
  float* partial = (float*)(ws + ((size_t)24 << 20));

  k_pp<<<1280, 256, 0, stream>>>(adj, x, w, partial, Yt);
  k_tn<<<1024, 256, 0, stream>>>(adj, partial, At);
  k_gemm<<<512, 256, 0, stream>>>(At, Yt, bias, out);
}

// Round 12
// 141.552 us; speedup vs baseline: 2.8021x; 1.0528x over previous
//
#include <hip/hip_runtime.h>
#include <cstddef>

typedef unsigned short u16;
typedef u16 u16x8 __attribute__((ext_vector_type(8)));
typedef __bf16 bf16x8 __attribute__((ext_vector_type(8)));
typedef float f32x4 __attribute__((ext_vector_type(4)));

static constexpr int V  = 2048;
static constexpr int DD = 64;   // D_IN == D_OUT

__device__ __forceinline__ u16 f2b(float f) {
  union { float f; unsigned int i; } x; x.f = f;
  return (u16)((x.i + 0x7fffu + ((x.i >> 16) & 1u)) >> 16);  // RNE
}

__device__ __forceinline__ void gll16(const void* g, void* l) {
  __builtin_amdgcn_global_load_lds(
      (const __attribute__((address_space(1))) void*)g,
      (__attribute__((address_space(3))) void*)l, 16, 0, 0);
}

// ---- K1 fused: blocks 0..255 = column-sum partials; 256..1279 = proj ----
// R12 = exact R6 configuration (session best: 140.6us). Session ledger:
//  - k_gemm schedules: R1 44.3 / R2 51.2 / R3 58.7 / R4 42.4 / R9 47.9
//    -> R4 form is the floor of the 2-phase 128^2 class at this shape.
//  - R8 cooperative mega-kernel: grid.sync ~115us each -> 300us. Dead.
//  - R5/R6: each extra launch ~5-10us; 3 launches is the dep-graph minimum.
__global__ __launch_bounds__(256) void k_pp(const float* __restrict__ adj,
                                            const float* __restrict__ x,
                                            const float* __restrict__ w,
                                            float* __restrict__ partial,
                                            u16* __restrict__ Yt) {
  __shared__ u16 WT[64 * 72];   // proj: W^T bf16, stride 72 (9 KB)
  int t = threadIdx.x;
  int bid = blockIdx.x;

  if (bid < 256) {
    // ---------- part: partial[rg][col] = sum of 64 adj rows ----------
    int rg = bid >> 3, cg = bid & 7;
    int col = cg * 256 + t;
    const float* p = adj + (size_t)(rg * 64) * V + col;
    float s = 0.f;
    for (int r = 0; r < 64; ++r) s += p[(size_t)r * V];
    partial[(size_t)rg * V + col] = s;
  } else {
    // ---------- proj (MFMA): Yt[(ab*64+e)][v] = sum_d W[d][e]*x[ab,v,d] ----
    int pb = bid - 256;
    int ab = pb >> 4;
    int v0 = (pb & 15) * 128;

    {
      const float4* pw = (const float4*)(w + t * 16);
      float4 c0 = pw[0], c1 = pw[1], c2 = pw[2], c3 = pw[3];
      float vals[16] = {c0.x, c0.y, c0.z, c0.w, c1.x, c1.y, c1.z, c1.w,
                        c2.x, c2.y, c2.z, c2.w, c3.x, c3.y, c3.z, c3.w};
      #pragma unroll
      for (int k = 0; k < 16; ++k) {
        int idx = t * 16 + k;             // idx = d*64 + e
        WT[(idx & 63) * 72 + (idx >> 6)] = f2b(vals[k]);
      }
    }
    __syncthreads();

    int lane = t & 63, wave = t >> 6;
    int q = lane >> 4, r = lane & 15;
    int vbase = v0 + wave * 32;

    bf16x8 a[4][2];
    #pragma unroll
    for (int i = 0; i < 4; ++i)
      #pragma unroll
      for (int kk = 0; kk < 2; ++kk)
        a[i][kk] = __builtin_bit_cast(bf16x8,
            *(const u16x8*)(WT + (i * 16 + r) * 72 + kk * 32 + q * 8));

    const f32x4 vzero = {0.f, 0.f, 0.f, 0.f};
    f32x4 acc[4][2];
    #pragma unroll
    for (int i = 0; i < 4; ++i) { acc[i][0] = vzero; acc[i][1] = vzero; }

    #pragma unroll
    for (int nt = 0; nt < 2; ++nt) {
      int v = vbase + nt * 16 + r;
      const float* xp = x + ((size_t)ab * V + v) * DD;
      #pragma unroll
      for (int kk = 0; kk < 2; ++kk) {
        const float4* p = (const float4*)(xp + kk * 32 + q * 8);
        float4 b0 = p[0], b1 = p[1];
        u16x8 bu;
        bu[0] = f2b(b0.x); bu[1] = f2b(b0.y); bu[2] = f2b(b0.z); bu[3] = f2b(b0.w);
        bu[4] = f2b(b1.x); bu[5] = f2b(b1.y); bu[6] = f2b(b1.z); bu[7] = f2b(b1.w);
        bf16x8 bf = __builtin_bit_cast(bf16x8, bu);
        #pragma unroll
        for (int i = 0; i < 4; ++i)
          acc[i][nt] = __builtin_amdgcn_mfma_f32_16x16x32_bf16(a[i][kk], bf, acc[i][nt], 0, 0, 0);
      }
    }

    #pragma unroll
    for (int i = 0; i < 4; ++i)
      #pragma unroll
      for (int nt = 0; nt < 2; ++nt) {
        int v = vbase + nt * 16 + r;
        #pragma unroll
        for (int reg = 0; reg < 4; ++reg) {
          int e = i * 16 + q * 4 + reg;
          Yt[(size_t)(ab * 64 + e) * V + v] = f2b(acc[i][nt][reg]);
        }
      }
  }
}

// ---- K2: tn tiles with inline rinv: At[j][v] = adj[v][j]*rinv[v]*rinv[j] --
// rinv from partial[32][2048] (256 KB, L2-hot): 32 adds per column.
__global__ __launch_bounds__(256) void k_tn(const float* __restrict__ adj,
                                            const float* __restrict__ partial,
                                            u16* __restrict__ At) {
  __shared__ float T[64][65];
  __shared__ float rvv[64], rvj[64];
  int t = threadIdx.x;
  int bid = blockIdx.x;
  int v0 = (bid & 31) * 64;
  int j0 = (bid >> 5) * 64;

  if (t < 128) {
    int col = (t < 64) ? (v0 + t) : (j0 + (t - 64));
    float s = 0.f;
    #pragma unroll
    for (int i = 0; i < 32; ++i) s += partial[(size_t)i * V + col];
    float rv = rsqrtf(s);
    if (t < 64) rvv[t] = rv; else rvj[t - 64] = rv;
  }
  __syncthreads();
  #pragma unroll
  for (int it = 0; it < 2; ++it) {
    int f = t + it * 256;
    int row = f >> 3;          // v offset
    int cc = (f & 7) * 8;      // j chunk
    float rv = rvv[row];
    const float4* p = (const float4*)(adj + (size_t)(v0 + row) * V + j0 + cc);
    float4 a0 = p[0], a1 = p[1];
    T[row][cc + 0] = a0.x * rv; T[row][cc + 1] = a0.y * rv;
    T[row][cc + 2] = a0.z * rv; T[row][cc + 3] = a0.w * rv;
    T[row][cc + 4] = a1.x * rv; T[row][cc + 5] = a1.y * rv;
    T[row][cc + 6] = a1.z * rv; T[row][cc + 7] = a1.w * rv;
  }
  __syncthreads();
  #pragma unroll
  for (int it = 0; it < 2; ++it) {
    int f = t + it * 256;
    int jr = f >> 3;           // j offset
    int vc = (f & 7) * 8;      // v chunk
    float rj = rvj[jr];
    u16x8 o;
    #pragma unroll
    for (int k = 0; k < 8; ++k) o[k] = f2b(T[vc + k][jr] * rj);
    *(u16x8*)(At + (size_t)(j0 + jr) * V + v0 + vc) = o;
  }
}

// ---- K3: OUT[j,n] = sum_v At[j,v]*Yt[n,v]; +bias, relu; FP32 out ----
// R4 form (best of 5 measured schedules: 42.4us / ~810 TF / MfmaUtil 30%).
// BM=BN=128, BK=64 dbuf 64 KB, 4 waves 64x64, 512 blocks = 2/CU.
// stage(next) before MFMA body; single vmcnt(0)+barrier per K-tile;
// XOR swizzle ch^=(row&7) both-sides (0 bank conflicts, R3/R10 verified).
static constexpr int ABUF  = 128 * 64;          // u16 units, 16 KB
static constexpr int BUFSZ = 2 * ABUF;          // 32 KB (A + B)

__global__ __launch_bounds__(256) void k_gemm(const u16* __restrict__ At,
                                              const u16* __restrict__ Yt,
                                              const float* __restrict__ bias,
                                              float* __restrict__ out) {
  __shared__ u16 lds[2 * BUFSZ];                // 64 KB
  const int t = threadIdx.x;
  const int bid = blockIdx.x;
  const int swz = (bid & 7) * 64 + (bid >> 3);  // XCD-chunked, bijective (512%8==0)
  const int m0 = (swz & 15) * 128;
  const int n0 = (swz >> 4) * 128;
  const int lane = t & 63, wave = t >> 6;
  const int wm = (wave & 1) * 64;
  const int wn = (wave >> 1) * 64;
  const int q = lane >> 4, r = lane & 15;

  auto stage = [&](int base, int k0) {
    #pragma unroll
    for (int l = 0; l < 4; ++l) {
      int g = l * 256 + t;
      int row = g >> 3;
      int ch = (g & 7) ^ (row & 7);
      gll16(At + (size_t)(m0 + row) * V + k0 + ch * 8, (void*)(lds + base + g * 8));
      gll16(Yt + (size_t)(n0 + row) * V + k0 + ch * 8, (void*)(lds + base + ABUF + g * 8));
    }
  };

  const f32x4 vzero = {0.f, 0.f, 0.f, 0.f};
  f32x4 acc[4][4];
  #pragma unroll
  for (int i = 0; i < 4; ++i)
    #pragma unroll
    for (int j = 0; j < 4; ++j) acc[i][j] = vzero;

  stage(0, 0);
  asm volatile("s_waitcnt vmcnt(0)" ::: "memory");
  __builtin_amdgcn_s_barrier();

  int cb = 0;
  for (int tt = 0; tt < 32; ++tt) {
    const int nb = cb ^ BUFSZ;
    if (tt < 31) stage(nb, (tt + 1) * 64);
    __builtin_amdgcn_sched_barrier(0);   // keep stage issues at phase top

    #pragma unroll
    for (int kk = 0; kk < 2; ++kk) {
      bf16x8 a[4], b[4];
      #pragma unroll
      for (int i = 0; i < 4; ++i) {
        int row = wm + i * 16 + r;
        int c = (kk * 4 + q) ^ (row & 7);
        a[i] = __builtin_bit_cast(bf16x8,
            *(const u16x8*)(lds + cb + row * 64 + c * 8));
      }
      #pragma unroll
      for (int j = 0; j < 4; ++j) {
        int row = wn + j * 16 + r;
        int c = (kk * 4 + q) ^ (row & 7);
        b[j] = __builtin_bit_cast(bf16x8,
            *(const u16x8*)(lds + cb + ABUF + row * 64 + c * 8));
      }
      __builtin_amdgcn_s_setprio(1);
      #pragma unroll
      for (int i = 0; i < 4; ++i)
        #pragma unroll
        for (int j = 0; j < 4; ++j)
          acc[i][j] = __builtin_amdgcn_mfma_f32_16x16x32_bf16(
              a[i], b[j], acc[i][j], 0, 0, 0);
      __builtin_amdgcn_s_setprio(0);
    }

    asm volatile("s_waitcnt vmcnt(0)" ::: "memory");
    __builtin_amdgcn_s_barrier();
    cb = nb;
  }

  #pragma unroll
  for (int j = 0; j < 4; ++j) {
    int n = n0 + wn + j * 16 + r;
    int e = n & 63;
    int ab = n >> 6;
    float bv = bias[e];
    float* ob = out + (size_t)ab * (V * DD);
    #pragma unroll
    for (int i = 0; i < 4; ++i) {
      #pragma unroll
      for (int reg = 0; reg < 4; ++reg) {
        int jj = m0 + wm + i * 16 + q * 4 + reg;
        ob[(size_t)jj * DD + e] = fmaxf(acc[i][j][reg] + bv, 0.f);
      }
    }
  }
}

extern "C" void kernel_launch(void* const* d_in, const int* in_sizes, int n_in,
                              void* d_out, int out_size, void* d_ws, size_t ws_size,
                              hipStream_t stream) {
  const float* adj  = (const float*)d_in[0];
  const float* x    = (const float*)d_in[1];
  const float* w    = (const float*)d_in[2];
  const float* bias = (const float*)d_in[3];
  float* out = (float*)d_out;

  // Workspace (24.25 MB):
  //   At      @ 0     : 2048*2048 bf16 = 8 MB    (live k_tn..k_gemm)
  //   Yt      @ 8 MB  : 4096*2048 bf16 = 16 MB   (live k_pp..k_gemm)
  //   partial @ 24 MB : 32*2048 f32 = 256 KB     (live k_pp..k_tn)
  char* ws = (char*)d_ws;
  u16*   At      = (u16*)ws;
  u16*   Yt      = (u16*)(ws + ((size_t)8 << 20));
  float* partial = (float*)(ws + ((size_t)24 << 20));

  k_pp<<<1280, 256, 0, stream>>>(adj, x, w, partial, Yt);
  k_tn<<<1024, 256, 0, stream>>>(adj, partial, At);
  k_gemm<<<512, 256, 0, stream>>>(At, Yt, bias, out);
}